// Round 8
// baseline (288.962 us; speedup 1.0000x reference)
//
#include <hip/hip_runtime.h>
#include <hip/hip_bf16.h>
#include <math.h>

#define DIMV 256
#define DV 32
#define QKVS 768   // interleaved row stride: q[256] | k[256] | v[256]

typedef __attribute__((ext_vector_type(8))) short bf16x8;
typedef __attribute__((ext_vector_type(4))) float f32x4;

#define EXPS(x) __expf(x)
#define SCORE_SCALE 0.17677669529663687f

static __device__ __forceinline__ unsigned short f2bf(float f) {
    unsigned x = __float_as_uint(f);
    x += 0x7FFF + ((x >> 16) & 1);   // round-to-nearest-even
    return (unsigned short)(x >> 16);
}
static __device__ __forceinline__ float bf2f(unsigned short u) {
    return __uint_as_float(((unsigned)u) << 16);
}

static __device__ __forceinline__ void async16(const void* g, void* lds) {
    __builtin_amdgcn_global_load_lds(
        (const __attribute__((address_space(1))) void*)g,
        (__attribute__((address_space(3))) void*)lds, 16, 0, 0);
}

// ------- conversions (x f32->bf16, 4 weight mats f32->bf16) + degree count -------

__global__ void cvt_all(const float* __restrict__ x, unsigned short* __restrict__ Xb, int nx4,
                        const float* __restrict__ Wq, const float* __restrict__ Wk,
                        const float* __restrict__ Wv, const float* __restrict__ Wo,
                        unsigned short* __restrict__ Wcat,
                        const int* __restrict__ dst, int* __restrict__ deg, int E) {
    int b = blockIdx.x, tid = threadIdx.x;
    if (b < 256) {
        // weights: 4 mats x 16384 float4, one float4 per thread
        const float* W = (b >> 6) == 0 ? Wq : (b >> 6) == 1 ? Wk : (b >> 6) == 2 ? Wv : Wo;
        int i = (b & 63) * 256 + tid;
        float4 v = ((const float4*)W)[i];
        ushort4 o;
        o.x = f2bf(v.x); o.y = f2bf(v.y); o.z = f2bf(v.z); o.w = f2bf(v.w);
        ((ushort4*)(Wcat + (size_t)(b >> 6) * 65536))[i] = o;
    } else {
        // x: grid-stride over float4s
        int nb = gridDim.x - 256;
        for (int i = (b - 256) * 256 + tid; i < nx4; i += nb * 256) {
            float4 v = ((const float4*)x)[i];
            ushort4 o;
            o.x = f2bf(v.x); o.y = f2bf(v.y); o.z = f2bf(v.z); o.w = f2bf(v.w);
            ((ushort4*)Xb)[i] = o;
        }
    }
    // fused degree count (grid-stride over E, all blocks)
    int nthr = gridDim.x * 256;
    for (int e = b * 256 + tid; e < E; e += nthr) atomicAdd(&deg[dst[e]], 1);
}

// ---------------- CSR scan (R3 config — measured fast) ----------------

__global__ void zero_i32(int* __restrict__ p, int n) {
    int i = blockIdx.x * blockDim.x + threadIdx.x;
    if (i < n) p[i] = 0;
}

__global__ void block_sum(const int* __restrict__ deg, int* __restrict__ bsum, int n) {
    __shared__ int sm[256];
    int i = blockIdx.x * 256 + threadIdx.x;
    sm[threadIdx.x] = (i < n) ? deg[i] : 0;
    __syncthreads();
    for (int s = 128; s > 0; s >>= 1) {
        if (threadIdx.x < s) sm[threadIdx.x] += sm[threadIdx.x + s];
        __syncthreads();
    }
    if (threadIdx.x == 0) bsum[blockIdx.x] = sm[0];
}

__global__ void scan_bsum(int* __restrict__ bsum, int nb) {
    if (threadIdx.x == 0) {
        int r = 0;
        for (int i = 0; i < nb; ++i) { int v = bsum[i]; bsum[i] = r; r += v; }
    }
}

__global__ void scan_final(const int* __restrict__ deg, const int* __restrict__ bsum,
                           int* __restrict__ offsets, int* __restrict__ cursor, int n) {
    __shared__ int sm[256];
    int i = blockIdx.x * 256 + threadIdx.x;
    int v = (i < n) ? deg[i] : 0;
    sm[threadIdx.x] = v;
    __syncthreads();
    for (int s = 1; s < 256; s <<= 1) {
        int t = (threadIdx.x >= s) ? sm[threadIdx.x - s] : 0;
        __syncthreads();
        sm[threadIdx.x] += t;
        __syncthreads();
    }
    int excl = sm[threadIdx.x] - v + bsum[blockIdx.x];
    if (i < n) { offsets[i] = excl; cursor[i] = excl; }
    if (i == n - 1) offsets[n] = excl + v;
}

// ---------------- m97-structure MFMA GEMM: C = A @ W^T + b, 128x128 tile ----------------
// A [M][256] bf16; W [nmat][256][256] bf16 (row-major, K contiguous). BK=32, 8 K-steps.
// LDS per buffer: A frags [0..512), B frags [512..1024); frag f=(row|col)*4+lkg at byte f*16
// -> both ds_read and DMA-dest are lane-linear 16B (conflict-free, R7-verified).
// K-loop (m97): { issue DMA(t+1) x4; vmcnt(4); barrier; ds_read+MFMA; barrier }.
// Stores ONLY in epilogue -> VMEM queue in-loop holds DMAs alone, count is exact.
// Leading scb blocks perform the edge scatter (R7-verified overlap trick).

template<bool OF32, int OSTRIDE, int MATSTRIDE, bool SCATTER>
__global__ __launch_bounds__(256)
void gemm128(const unsigned short* __restrict__ A,
             const unsigned short* __restrict__ Wbase,
             const float* __restrict__ b0, const float* __restrict__ b1,
             const float* __restrict__ b2,
             void* __restrict__ Cout, int M, int nct, int scb,
             const int* __restrict__ esrc, const int* __restrict__ edst,
             int* __restrict__ cursor, int* __restrict__ perm_src, int E) {
    if (SCATTER && (int)blockIdx.x < scb) {
        int nthr = scb * 256;
        for (int e = (int)blockIdx.x * 256 + (int)threadIdx.x; e < E; e += nthr)
            perm_src[atomicAdd(&cursor[edst[e]], 1)] = esrc[e];
        return;
    }
    __shared__ unsigned short lds[2][8192];   // 2 x 16 KB: A frags | B frags
    const int bid = (int)blockIdx.x - (SCATTER ? scb : 0);
    const int rb = bid / nct, ct = bid % nct;
    const int mat = ct >> 1, cm = ct & 1;
    const int tid = threadIdx.x, w = tid >> 6, lane = tid & 63;
    const int lrow = lane & 15, lkg = lane >> 4;
    const unsigned short* Wm = Wbase + (size_t)mat * 65536;
    const int row0 = rb * 128;

    // per-lane DMA source byte-offsets for K-step 0 (frag f = w*128 + j*64 + lane)
    unsigned srcA[2], srcB[2];
    #pragma unroll
    for (int j = 0; j < 2; ++j) {
        unsigned f = (unsigned)(w * 128 + j * 64 + lane);
        int ra = min(row0 + (int)(f >> 2), M - 1);
        srcA[j] = (unsigned)ra * 512u + (f & 3u) * 16u;
        srcB[j] = ((unsigned)cm * 128u + (f >> 2)) * 512u + (f & 3u) * 16u;
    }

    // stage K-step 0 into buffer 0
    #pragma unroll
    for (int j = 0; j < 2; ++j) {
        async16((const char*)A  + srcA[j], (char*)&lds[0][0] + (w * 2048 + j * 1024));
        async16((const char*)Wm + srcB[j], (char*)&lds[0][0] + 8192 + (w * 2048 + j * 1024));
    }

    f32x4 acc[2][8] = {};
    #pragma unroll
    for (int t = 0; t < 8; ++t) {
        if (t + 1 < 8) {
            #pragma unroll
            for (int j = 0; j < 2; ++j) {
                async16((const char*)A  + srcA[j] + (unsigned)(t + 1) * 64u,
                        (char*)&lds[(t + 1) & 1][0] + (w * 2048 + j * 1024));
                async16((const char*)Wm + srcB[j] + (unsigned)(t + 1) * 64u,
                        (char*)&lds[(t + 1) & 1][0] + 8192 + (w * 2048 + j * 1024));
            }
            asm volatile("s_waitcnt vmcnt(4)" ::: "memory");   // step-t DMAs retired
        } else {
            asm volatile("s_waitcnt vmcnt(0)" ::: "memory");
        }
        __builtin_amdgcn_s_barrier();

        const char* base = (const char*)&lds[t & 1][0];
        bf16x8 aF0 = *(const bf16x8*)(base + w * 2048 + (lrow * 4 + lkg) * 16);
        bf16x8 aF1 = *(const bf16x8*)(base + w * 2048 + 1024 + (lrow * 4 + lkg) * 16);
        #pragma unroll
        for (int n = 0; n < 8; ++n) {
            bf16x8 bF = *(const bf16x8*)(base + 8192 + n * 1024 + (lrow * 4 + lkg) * 16);
            acc[0][n] = __builtin_amdgcn_mfma_f32_16x16x32_bf16(aF0, bF, acc[0][n], 0, 0, 0);
            acc[1][n] = __builtin_amdgcn_mfma_f32_16x16x32_bf16(aF1, bF, acc[1][n], 0, 0, 0);
        }
        __builtin_amdgcn_s_barrier();   // all reads of buf[t&1] done before reuse
    }

    // epilogue: bias + store (16 values/thread, once)
    const float* bp = (mat == 0) ? b0 : (mat == 1 ? b1 : b2);
    #pragma unroll
    for (int n = 0; n < 8; ++n) {
        float bias = bp[cm * 128 + n * 16 + lrow];
        unsigned ccol = (unsigned)(mat * MATSTRIDE + cm * 128 + n * 16 + lrow);
        #pragma unroll
        for (int m = 0; m < 2; ++m) {
            #pragma unroll
            for (int r = 0; r < 4; ++r) {
                int row = row0 + w * 32 + m * 16 + lkg * 4 + r;
                if (row < M) {
                    float val = acc[m][n][r] + bias;
                    if (OF32)
                        ((float*)Cout)[(size_t)row * OSTRIDE + ccol] = val;
                    else
                        ((unsigned short*)Cout)[(size_t)row * OSTRIDE + ccol] = f2bf(val);
                }
            }
        }
    }
}

// ---------------- per-node edge-softmax attention (unchanged, measured 114 µs) ----

__global__ __launch_bounds__(256)
void node_attn(const unsigned short* __restrict__ QKV,
               const int* __restrict__ offsets, const int* __restrict__ perm_src,
               unsigned short* __restrict__ attn, int N) {
    int wid = blockIdx.x * (blockDim.x >> 6) + (threadIdx.x >> 6);
    if (wid >= N) return;
    int lane = threadIdx.x & 63;
    unsigned col = (unsigned)((lane >> 3) * DV + (lane & 7) * 4);

    ushort4 kr = *(const ushort4*)(QKV + (size_t)wid * QKVS + 256 + col);
    float k0 = bf2f(kr.x) * SCORE_SCALE, k1 = bf2f(kr.y) * SCORE_SCALE;
    float k2 = bf2f(kr.z) * SCORE_SCALE, k3 = bf2f(kr.w) * SCORE_SCALE;

    float mA = -INFINITY, lA = 0.f, aA0 = 0.f, aA1 = 0.f, aA2 = 0.f, aA3 = 0.f;
    float mB = -INFINITY, lB = 0.f, aB0 = 0.f, aB1 = 0.f, aB2 = 0.f, aB3 = 0.f;

    auto upd = [&](ushort4 qr, ushort4 vr, float& m, float& l,
                   float& a0, float& a1, float& a2, float& a3) {
        float d = bf2f(qr.x) * k0 + bf2f(qr.y) * k1 + bf2f(qr.z) * k2 + bf2f(qr.w) * k3;
        d += __shfl_xor(d, 1); d += __shfl_xor(d, 2); d += __shfl_xor(d, 4);
        float mn = fmaxf(m, d);
        float sc = EXPS(m - mn);
        float pe = EXPS(d - mn);
        l = l * sc + pe;
        a0 = a0 * sc + pe * bf2f(vr.x);
        a1 = a1 * sc + pe * bf2f(vr.y);
        a2 = a2 * sc + pe * bf2f(vr.z);
        a3 = a3 * sc + pe * bf2f(vr.w);
        m = mn;
    };

    int e0 = offsets[wid], e1 = offsets[wid + 1];
    int rem = e1 - e0;
    int S = rem >> 1;
    int p = e0;

    if (S >= 1) {
        unsigned o0 = (unsigned)perm_src[p] * QKVS + col;
        unsigned o1 = (unsigned)perm_src[p + 1] * QKVS + col;
        ushort4 qA0 = *(const ushort4*)(QKV + o0);
        ushort4 vA0 = *(const ushort4*)(QKV + o0 + 512);
        ushort4 qA1 = *(const ushort4*)(QKV + o1);
        ushort4 vA1 = *(const ushort4*)(QKV + o1 + 512);
        unsigned n0 = 0, n1 = 0;
        if (S >= 2) {
            n0 = (unsigned)perm_src[p + 2] * QKVS + col;
            n1 = (unsigned)perm_src[p + 3] * QKVS + col;
        }
        ushort4 qB0, qB1, vB0, vB1;

        int s = 0;
        while (s + 2 <= S) {
            qB0 = *(const ushort4*)(QKV + n0);
            vB0 = *(const ushort4*)(QKV + n0 + 512);
            qB1 = *(const ushort4*)(QKV + n1);
            vB1 = *(const ushort4*)(QKV + n1 + 512);
            if (s + 2 < S) {
                n0 = (unsigned)perm_src[p + 2 * s + 4] * QKVS + col;
                n1 = (unsigned)perm_src[p + 2 * s + 5] * QKVS + col;
            }
            upd(qA0, vA0, mA, lA, aA0, aA1, aA2, aA3);
            upd(qA1, vA1, mB, lB, aB0, aB1, aB2, aB3);

            if (s + 2 < S) {
                qA0 = *(const ushort4*)(QKV + n0);
                vA0 = *(const ushort4*)(QKV + n0 + 512);
                qA1 = *(const ushort4*)(QKV + n1);
                vA1 = *(const ushort4*)(QKV + n1 + 512);
                if (s + 3 < S) {
                    n0 = (unsigned)perm_src[p + 2 * s + 6] * QKVS + col;
                    n1 = (unsigned)perm_src[p + 2 * s + 7] * QKVS + col;
                }
            }
            upd(qB0, vB0, mA, lA, aA0, aA1, aA2, aA3);
            upd(qB1, vB1, mB, lB, aB0, aB1, aB2, aB3);
            s += 2;
        }
        if (s < S) {
            upd(qA0, vA0, mA, lA, aA0, aA1, aA2, aA3);
            upd(qA1, vA1, mB, lB, aB0, aB1, aB2, aB3);
        }
    }
    if (rem & 1) {
        unsigned o0 = (unsigned)perm_src[e1 - 1] * QKVS + col;
        ushort4 q0 = *(const ushort4*)(QKV + o0);
        ushort4 v0 = *(const ushort4*)(QKV + o0 + 512);
        upd(q0, v0, mA, lA, aA0, aA1, aA2, aA3);
    }

    float mn = fmaxf(mA, mB);
    float scA = (lA > 0.f) ? EXPS(mA - mn) : 0.f;
    float scB = (lB > 0.f) ? EXPS(mB - mn) : 0.f;
    float l = lA * scA + lB * scB;
    float o0 = aA0 * scA + aB0 * scB;
    float o1 = aA1 * scA + aB1 * scB;
    float o2 = aA2 * scA + aB2 * scB;
    float o3 = aA3 * scA + aB3 * scB;
    float inv = (l > 0.f) ? 1.f / l : 0.f;

    ushort4 o;
    o.x = f2bf(o0 * inv); o.y = f2bf(o1 * inv); o.z = f2bf(o2 * inv); o.w = f2bf(o3 * inv);
    *(ushort4*)(attn + (size_t)wid * DIMV + col) = o;
}

// ---------------- launcher ----------------

extern "C" void kernel_launch(void* const* d_in, const int* in_sizes, int n_in,
                              void* d_out, int out_size, void* d_ws, size_t ws_size,
                              hipStream_t stream) {
    const float* x  = (const float*)d_in[0];
    const float* Wq = (const float*)d_in[1];
    const float* bq = (const float*)d_in[2];
    const float* Wk = (const float*)d_in[3];
    const float* bk = (const float*)d_in[4];
    const float* Wv = (const float*)d_in[5];
    const float* bv = (const float*)d_in[6];
    const float* Wo = (const float*)d_in[7];
    const float* bo = (const float*)d_in[8];
    const int* src  = (const int*)d_in[9];
    const int* dst  = (const int*)d_in[10];
    int N = in_sizes[0] / DIMV;
    int E = in_sizes[9];
    float* out = (float*)d_out;

    char* p = (char*)d_ws;
    auto alloc = [&](size_t bytes) {
        char* r = p;
        p += (bytes + 255) & ~(size_t)255;
        return r;
    };
    unsigned short* Wcat = (unsigned short*)alloc((size_t)4 * 65536 * 2);   // [Wq|Wk|Wv|Wo] bf16
    unsigned short* Xb   = (unsigned short*)alloc((size_t)N * DIMV * 2);    // x in bf16
    unsigned short* QKV  = (unsigned short*)alloc((size_t)N * QKVS * 2);    // interleaved q|k|v
    unsigned short* attn = (unsigned short*)alloc((size_t)N * DIMV * 2);
    int* deg             = (int*)alloc((size_t)N * 4);
    int* offsets         = (int*)alloc((size_t)(N + 1) * 4);
    int* cursor          = (int*)alloc((size_t)N * 4);
    int* perm_src        = (int*)alloc((size_t)E * 4);
    int* bsum            = (int*)alloc((size_t)1024 * 4);

    int nb = (N + 255) / 256;
    zero_i32<<<nb, 256, 0, stream>>>(deg, N);

    // conversions (W, x) + fused degree count
    int nx4 = N * DIMV / 4;
    cvt_all<<<256 + 768, 256, 0, stream>>>(x, Xb, nx4, Wq, Wk, Wv, Wo, Wcat, dst, deg, E);

    // scan: deg -> offsets/cursor
    block_sum<<<nb, 256, 0, stream>>>(deg, bsum, N);
    scan_bsum<<<1, 64, 0, stream>>>(bsum, nb);
    scan_final<<<nb, 256, 0, stream>>>(deg, bsum, offsets, cursor, N);

    // QKV projection (m97 structure) + leading scatter blocks
    int rblocks = (N + 127) / 128;
    const int SCB = 160;
    gemm128<false, QKVS, 256, true><<<SCB + rblocks * 6, 256, 0, stream>>>(
        Xb, Wcat, bq, bk, bv, QKV, N, 6, SCB, src, dst, cursor, perm_src, E);

    node_attn<<<(N + 3) / 4, 256, 0, stream>>>(QKV, offsets, perm_src, attn, N);

    // output projection: attn(bf16) -> out(f32)
    gemm128<true, DIMV, 0, false><<<rblocks * 2, 256, 0, stream>>>(
        attn, Wcat + (size_t)3 * 65536, bo, bo, bo, out, N, 2, 0,
        nullptr, nullptr, nullptr, nullptr, 0);
}

// Round 9
// 274.587 us; speedup vs baseline: 1.0524x; 1.0524x over previous
//
#include <hip/hip_runtime.h>
#include <hip/hip_bf16.h>
#include <math.h>

#define DIMV 256
#define DV 32
#define QKVS 768   // interleaved row stride: q[256] | k[256] | v[256]

typedef __attribute__((ext_vector_type(8))) short bf16x8;
typedef __attribute__((ext_vector_type(4))) float f32x4;

#define EXPS(x) __expf(x)
#define SCORE_SCALE 0.17677669529663687f

static __device__ __forceinline__ unsigned short f2bf(float f) {
    unsigned x = __float_as_uint(f);
    x += 0x7FFF + ((x >> 16) & 1);   // round-to-nearest-even
    return (unsigned short)(x >> 16);
}
static __device__ __forceinline__ float bf2f(unsigned short u) {
    return __uint_as_float(((unsigned)u) << 16);
}

static __device__ __forceinline__ void async16(const void* g, void* lds) {
    __builtin_amdgcn_global_load_lds(
        (const __attribute__((address_space(1))) void*)g,
        (__attribute__((address_space(3))) void*)lds, 16, 0, 0);
}

// ------- conversions (x f32->bf16, 4 weight mats f32->bf16) + degree count -------

__global__ void cvt_all(const float* __restrict__ x, unsigned short* __restrict__ Xb, int nx4,
                        const float* __restrict__ Wq, const float* __restrict__ Wk,
                        const float* __restrict__ Wv, const float* __restrict__ Wo,
                        unsigned short* __restrict__ Wcat,
                        const int* __restrict__ dst, int* __restrict__ deg, int E) {
    int b = blockIdx.x, tid = threadIdx.x;
    if (b < 256) {
        const float* W = (b >> 6) == 0 ? Wq : (b >> 6) == 1 ? Wk : (b >> 6) == 2 ? Wv : Wo;
        int i = (b & 63) * 256 + tid;
        float4 v = ((const float4*)W)[i];
        ushort4 o;
        o.x = f2bf(v.x); o.y = f2bf(v.y); o.z = f2bf(v.z); o.w = f2bf(v.w);
        ((ushort4*)(Wcat + (size_t)(b >> 6) * 65536))[i] = o;
    } else {
        int nb = gridDim.x - 256;
        for (int i = (b - 256) * 256 + tid; i < nx4; i += nb * 256) {
            float4 v = ((const float4*)x)[i];
            ushort4 o;
            o.x = f2bf(v.x); o.y = f2bf(v.y); o.z = f2bf(v.z); o.w = f2bf(v.w);
            ((ushort4*)Xb)[i] = o;
        }
    }
    int nthr = gridDim.x * 256;
    for (int e = b * 256 + tid; e < E; e += nthr) atomicAdd(&deg[dst[e]], 1);
}

// ---------------- CSR scan (R3 config — measured fast) ----------------

__global__ void zero_i32(int* __restrict__ p, int n) {
    int i = blockIdx.x * blockDim.x + threadIdx.x;
    if (i < n) p[i] = 0;
}

__global__ void block_sum(const int* __restrict__ deg, int* __restrict__ bsum, int n) {
    __shared__ int sm[256];
    int i = blockIdx.x * 256 + threadIdx.x;
    sm[threadIdx.x] = (i < n) ? deg[i] : 0;
    __syncthreads();
    for (int s = 128; s > 0; s >>= 1) {
        if (threadIdx.x < s) sm[threadIdx.x] += sm[threadIdx.x + s];
        __syncthreads();
    }
    if (threadIdx.x == 0) bsum[blockIdx.x] = sm[0];
}

__global__ void scan_bsum(int* __restrict__ bsum, int nb) {
    if (threadIdx.x == 0) {
        int r = 0;
        for (int i = 0; i < nb; ++i) { int v = bsum[i]; bsum[i] = r; r += v; }
    }
}

__global__ void scan_final(const int* __restrict__ deg, const int* __restrict__ bsum,
                           int* __restrict__ offsets, int* __restrict__ cursor, int n) {
    __shared__ int sm[256];
    int i = blockIdx.x * 256 + threadIdx.x;
    int v = (i < n) ? deg[i] : 0;
    sm[threadIdx.x] = v;
    __syncthreads();
    for (int s = 1; s < 256; s <<= 1) {
        int t = (threadIdx.x >= s) ? sm[threadIdx.x - s] : 0;
        __syncthreads();
        sm[threadIdx.x] += t;
        __syncthreads();
    }
    int excl = sm[threadIdx.x] - v + bsum[blockIdx.x];
    if (i < n) { offsets[i] = excl; cursor[i] = excl; }
    if (i == n - 1) offsets[n] = excl + v;
}

// ---------------- m97-structure MFMA GEMM, XCD-chunked work mapping ----------------
// Work-id wid = rb*nct + ct (the nct blocks sharing one A-tile are CONSECUTIVE).
// Physical blockIdx round-robins XCDs (xcd = phys%8), so we remap bijectively:
// wid = chunk_base(xcd) + phys/8  ->  consecutive wids (same A-tile) execute on
// the SAME XCD, temporally adjacent -> A-tile fetched once into that XCD's L2,
// hit by the other nct-1 blocks. Kills the 6x A re-read (R8's invisible wall).
// K-loop unchanged from R8 (BK=32, counted vmcnt(4), stores only in epilogue).

template<bool OF32, int OSTRIDE, int MATSTRIDE, bool SCATTER>
__global__ __launch_bounds__(256)
void gemm128(const unsigned short* __restrict__ A,
             const unsigned short* __restrict__ Wbase,
             const float* __restrict__ b0, const float* __restrict__ b1,
             const float* __restrict__ b2,
             void* __restrict__ Cout, int M, int nct, int scb,
             const int* __restrict__ esrc, const int* __restrict__ edst,
             int* __restrict__ cursor, int* __restrict__ perm_src, int E) {
    if (SCATTER && (int)blockIdx.x < scb) {
        int nthr = scb * 256;
        for (int e = (int)blockIdx.x * 256 + (int)threadIdx.x; e < E; e += nthr)
            perm_src[atomicAdd(&cursor[edst[e]], 1)] = esrc[e];
        return;
    }
    __shared__ unsigned short lds[2][8192];   // 2 x 16 KB: A frags | B frags

    // bijective XCD-chunk remap (m204 variant)
    const int phys = (int)blockIdx.x - (SCATTER ? scb : 0);
    const int nwg  = (int)gridDim.x - (SCATTER ? scb : 0);
    const int qq = nwg >> 3, rr = nwg & 7;
    const int xcd = phys & 7, slot = phys >> 3;
    const int wid = (xcd < rr ? xcd * (qq + 1) : rr * (qq + 1) + (xcd - rr) * qq) + slot;

    const int rb = wid / nct, ct = wid % nct;
    const int mat = ct >> 1, cm = ct & 1;
    const int tid = threadIdx.x, w = tid >> 6, lane = tid & 63;
    const int lrow = lane & 15, lkg = lane >> 4;
    const unsigned short* Wm = Wbase + (size_t)mat * 65536;
    const int row0 = rb * 128;

    unsigned srcA[2], srcB[2];
    #pragma unroll
    for (int j = 0; j < 2; ++j) {
        unsigned f = (unsigned)(w * 128 + j * 64 + lane);
        int ra = min(row0 + (int)(f >> 2), M - 1);
        srcA[j] = (unsigned)ra * 512u + (f & 3u) * 16u;
        srcB[j] = ((unsigned)cm * 128u + (f >> 2)) * 512u + (f & 3u) * 16u;
    }

    #pragma unroll
    for (int j = 0; j < 2; ++j) {
        async16((const char*)A  + srcA[j], (char*)&lds[0][0] + (w * 2048 + j * 1024));
        async16((const char*)Wm + srcB[j], (char*)&lds[0][0] + 8192 + (w * 2048 + j * 1024));
    }

    f32x4 acc[2][8] = {};
    #pragma unroll
    for (int t = 0; t < 8; ++t) {
        if (t + 1 < 8) {
            #pragma unroll
            for (int j = 0; j < 2; ++j) {
                async16((const char*)A  + srcA[j] + (unsigned)(t + 1) * 64u,
                        (char*)&lds[(t + 1) & 1][0] + (w * 2048 + j * 1024));
                async16((const char*)Wm + srcB[j] + (unsigned)(t + 1) * 64u,
                        (char*)&lds[(t + 1) & 1][0] + 8192 + (w * 2048 + j * 1024));
            }
            asm volatile("s_waitcnt vmcnt(4)" ::: "memory");
        } else {
            asm volatile("s_waitcnt vmcnt(0)" ::: "memory");
        }
        __builtin_amdgcn_s_barrier();

        const char* base = (const char*)&lds[t & 1][0];
        bf16x8 aF0 = *(const bf16x8*)(base + w * 2048 + (lrow * 4 + lkg) * 16);
        bf16x8 aF1 = *(const bf16x8*)(base + w * 2048 + 1024 + (lrow * 4 + lkg) * 16);
        #pragma unroll
        for (int n = 0; n < 8; ++n) {
            bf16x8 bF = *(const bf16x8*)(base + 8192 + n * 1024 + (lrow * 4 + lkg) * 16);
            acc[0][n] = __builtin_amdgcn_mfma_f32_16x16x32_bf16(aF0, bF, acc[0][n], 0, 0, 0);
            acc[1][n] = __builtin_amdgcn_mfma_f32_16x16x32_bf16(aF1, bF, acc[1][n], 0, 0, 0);
        }
        __builtin_amdgcn_s_barrier();
    }

    const float* bp = (mat == 0) ? b0 : (mat == 1 ? b1 : b2);
    #pragma unroll
    for (int n = 0; n < 8; ++n) {
        float bias = bp[cm * 128 + n * 16 + lrow];
        unsigned ccol = (unsigned)(mat * MATSTRIDE + cm * 128 + n * 16 + lrow);
        #pragma unroll
        for (int m = 0; m < 2; ++m) {
            #pragma unroll
            for (int r = 0; r < 4; ++r) {
                int row = row0 + w * 32 + m * 16 + lkg * 4 + r;
                if (row < M) {
                    float val = acc[m][n][r] + bias;
                    if (OF32)
                        ((float*)Cout)[(size_t)row * OSTRIDE + ccol] = val;
                    else
                        ((unsigned short*)Cout)[(size_t)row * OSTRIDE + ccol] = f2bf(val);
                }
            }
        }
    }
}

// ---------------- per-node edge-softmax attention (unchanged, measured ~115 µs) ----

__global__ __launch_bounds__(256)
void node_attn(const unsigned short* __restrict__ QKV,
               const int* __restrict__ offsets, const int* __restrict__ perm_src,
               unsigned short* __restrict__ attn, int N) {
    int wid = blockIdx.x * (blockDim.x >> 6) + (threadIdx.x >> 6);
    if (wid >= N) return;
    int lane = threadIdx.x & 63;
    unsigned col = (unsigned)((lane >> 3) * DV + (lane & 7) * 4);

    ushort4 kr = *(const ushort4*)(QKV + (size_t)wid * QKVS + 256 + col);
    float k0 = bf2f(kr.x) * SCORE_SCALE, k1 = bf2f(kr.y) * SCORE_SCALE;
    float k2 = bf2f(kr.z) * SCORE_SCALE, k3 = bf2f(kr.w) * SCORE_SCALE;

    float mA = -INFINITY, lA = 0.f, aA0 = 0.f, aA1 = 0.f, aA2 = 0.f, aA3 = 0.f;
    float mB = -INFINITY, lB = 0.f, aB0 = 0.f, aB1 = 0.f, aB2 = 0.f, aB3 = 0.f;

    auto upd = [&](ushort4 qr, ushort4 vr, float& m, float& l,
                   float& a0, float& a1, float& a2, float& a3) {
        float d = bf2f(qr.x) * k0 + bf2f(qr.y) * k1 + bf2f(qr.z) * k2 + bf2f(qr.w) * k3;
        d += __shfl_xor(d, 1); d += __shfl_xor(d, 2); d += __shfl_xor(d, 4);
        float mn = fmaxf(m, d);
        float sc = EXPS(m - mn);
        float pe = EXPS(d - mn);
        l = l * sc + pe;
        a0 = a0 * sc + pe * bf2f(vr.x);
        a1 = a1 * sc + pe * bf2f(vr.y);
        a2 = a2 * sc + pe * bf2f(vr.z);
        a3 = a3 * sc + pe * bf2f(vr.w);
        m = mn;
    };

    int e0 = offsets[wid], e1 = offsets[wid + 1];
    int rem = e1 - e0;
    int S = rem >> 1;
    int p = e0;

    if (S >= 1) {
        unsigned o0 = (unsigned)perm_src[p] * QKVS + col;
        unsigned o1 = (unsigned)perm_src[p + 1] * QKVS + col;
        ushort4 qA0 = *(const ushort4*)(QKV + o0);
        ushort4 vA0 = *(const ushort4*)(QKV + o0 + 512);
        ushort4 qA1 = *(const ushort4*)(QKV + o1);
        ushort4 vA1 = *(const ushort4*)(QKV + o1 + 512);
        unsigned n0 = 0, n1 = 0;
        if (S >= 2) {
            n0 = (unsigned)perm_src[p + 2] * QKVS + col;
            n1 = (unsigned)perm_src[p + 3] * QKVS + col;
        }
        ushort4 qB0, qB1, vB0, vB1;

        int s = 0;
        while (s + 2 <= S) {
            qB0 = *(const ushort4*)(QKV + n0);
            vB0 = *(const ushort4*)(QKV + n0 + 512);
            qB1 = *(const ushort4*)(QKV + n1);
            vB1 = *(const ushort4*)(QKV + n1 + 512);
            if (s + 2 < S) {
                n0 = (unsigned)perm_src[p + 2 * s + 4] * QKVS + col;
                n1 = (unsigned)perm_src[p + 2 * s + 5] * QKVS + col;
            }
            upd(qA0, vA0, mA, lA, aA0, aA1, aA2, aA3);
            upd(qA1, vA1, mB, lB, aB0, aB1, aB2, aB3);

            if (s + 2 < S) {
                qA0 = *(const ushort4*)(QKV + n0);
                vA0 = *(const ushort4*)(QKV + n0 + 512);
                qA1 = *(const ushort4*)(QKV + n1);
                vA1 = *(const ushort4*)(QKV + n1 + 512);
                if (s + 3 < S) {
                    n0 = (unsigned)perm_src[p + 2 * s + 6] * QKVS + col;
                    n1 = (unsigned)perm_src[p + 2 * s + 7] * QKVS + col;
                }
            }
            upd(qB0, vB0, mA, lA, aA0, aA1, aA2, aA3);
            upd(qB1, vB1, mB, lB, aB0, aB1, aB2, aB3);
            s += 2;
        }
        if (s < S) {
            upd(qA0, vA0, mA, lA, aA0, aA1, aA2, aA3);
            upd(qA1, vA1, mB, lB, aB0, aB1, aB2, aB3);
        }
    }
    if (rem & 1) {
        unsigned o0 = (unsigned)perm_src[e1 - 1] * QKVS + col;
        ushort4 q0 = *(const ushort4*)(QKV + o0);
        ushort4 v0 = *(const ushort4*)(QKV + o0 + 512);
        upd(q0, v0, mA, lA, aA0, aA1, aA2, aA3);
    }

    float mn = fmaxf(mA, mB);
    float scA = (lA > 0.f) ? EXPS(mA - mn) : 0.f;
    float scB = (lB > 0.f) ? EXPS(mB - mn) : 0.f;
    float l = lA * scA + lB * scB;
    float o0 = aA0 * scA + aB0 * scB;
    float o1 = aA1 * scA + aB1 * scB;
    float o2 = aA2 * scA + aB2 * scB;
    float o3 = aA3 * scA + aB3 * scB;
    float inv = (l > 0.f) ? 1.f / l : 0.f;

    ushort4 o;
    o.x = f2bf(o0 * inv); o.y = f2bf(o1 * inv); o.z = f2bf(o2 * inv); o.w = f2bf(o3 * inv);
    *(ushort4*)(attn + (size_t)wid * DIMV + col) = o;
}

// ---------------- launcher ----------------

extern "C" void kernel_launch(void* const* d_in, const int* in_sizes, int n_in,
                              void* d_out, int out_size, void* d_ws, size_t ws_size,
                              hipStream_t stream) {
    const float* x  = (const float*)d_in[0];
    const float* Wq = (const float*)d_in[1];
    const float* bq = (const float*)d_in[2];
    const float* Wk = (const float*)d_in[3];
    const float* bk = (const float*)d_in[4];
    const float* Wv = (const float*)d_in[5];
    const float* bv = (const float*)d_in[6];
    const float* Wo = (const float*)d_in[7];
    const float* bo = (const float*)d_in[8];
    const int* src  = (const int*)d_in[9];
    const int* dst  = (const int*)d_in[10];
    int N = in_sizes[0] / DIMV;
    int E = in_sizes[9];
    float* out = (float*)d_out;

    char* p = (char*)d_ws;
    auto alloc = [&](size_t bytes) {
        char* r = p;
        p += (bytes + 255) & ~(size_t)255;
        return r;
    };
    unsigned short* Wcat = (unsigned short*)alloc((size_t)4 * 65536 * 2);   // [Wq|Wk|Wv|Wo] bf16
    unsigned short* Xb   = (unsigned short*)alloc((size_t)N * DIMV * 2);    // x in bf16
    unsigned short* QKV  = (unsigned short*)alloc((size_t)N * QKVS * 2);    // interleaved q|k|v
    unsigned short* attn = (unsigned short*)alloc((size_t)N * DIMV * 2);
    int* deg             = (int*)alloc((size_t)N * 4);
    int* offsets         = (int*)alloc((size_t)(N + 1) * 4);
    int* cursor          = (int*)alloc((size_t)N * 4);
    int* perm_src        = (int*)alloc((size_t)E * 4);
    int* bsum            = (int*)alloc((size_t)1024 * 4);

    int nb = (N + 255) / 256;
    zero_i32<<<nb, 256, 0, stream>>>(deg, N);

    // conversions (W, x) + fused degree count
    int nx4 = N * DIMV / 4;
    cvt_all<<<256 + 768, 256, 0, stream>>>(x, Xb, nx4, Wq, Wk, Wv, Wo, Wcat, dst, deg, E);

    // scan: deg -> offsets/cursor
    block_sum<<<nb, 256, 0, stream>>>(deg, bsum, N);
    scan_bsum<<<1, 64, 0, stream>>>(bsum, nb);
    scan_final<<<nb, 256, 0, stream>>>(deg, bsum, offsets, cursor, N);

    // QKV projection (m97 structure + XCD-chunked mapping) + leading scatter blocks
    int rblocks = (N + 127) / 128;
    const int SCB = 160;
    gemm128<false, QKVS, 256, true><<<SCB + rblocks * 6, 256, 0, stream>>>(
        Xb, Wcat, bq, bk, bv, QKV, N, 6, SCB, src, dst, cursor, perm_src, E);

    node_attn<<<(N + 3) / 4, 256, 0, stream>>>(QKV, offsets, perm_src, attn, N);

    // output projection: attn(bf16) -> out(f32)
    gemm128<true, DIMV, 0, false><<<rblocks * 2, 256, 0, stream>>>(
        attn, Wcat + (size_t)3 * 65536, bo, bo, bo, out, N, 2, 0,
        nullptr, nullptr, nullptr, nullptr, 0);
}